// Round 2
// baseline (297.404 us; speedup 1.0000x reference)
//
#include <hip/hip_runtime.h>

#define NN 2048   // factor dim
#define KK 16     // nonzeros per row

// ---------------------------------------------------------------------------
// Stage A: compose W0 @ W1 into per-column coefficient table.
// W01[c1][i] = coefficient of x[s1' + 128*i] in y1[c1], s1' = (c1-1) mod 128.
// ---------------------------------------------------------------------------
__global__ __launch_bounds__(256) void sfd_compose01(const float* __restrict__ v0,
                                                     const float* __restrict__ v1,
                                                     float* __restrict__ w01) {
  int tid = blockIdx.x * 256 + threadIdx.x;   // 32768 threads: (c1, i)
  int c1 = tid >> 4;
  int i  = tid & 15;
  int cm = (c1 + NN - 1) & (NN - 1);          // (c1 - 1) mod N
  int s1 = cm & 127;
  int t1 = cm >> 7;
  int rx = s1 + (i << 7);
  float acc = 0.f;
#pragma unroll
  for (int k1 = 0; k1 < 16; ++k1) {
    int r0 = (cm - (k1 << 7)) & (NN - 1);
    int k0 = (t1 - k1 - i) & 15;
    acc = fmaf(v1[r0 * 16 + k1], v0[rx * 16 + k0], acc);
  }
  w01[c1 * 16 + i] = acc;
}

// ---------------------------------------------------------------------------
// Stage B: compose (W0@W1) @ W2, fold in scaling, store residue-major:
// mcl[((s*16 + j)*16) + i]  for col c = s + 128*j, coefficient of
// x[((c-3) mod 128) + 128*i].
// ---------------------------------------------------------------------------
__global__ __launch_bounds__(256) void sfd_compose012(const float* __restrict__ v2,
                                                      const float* __restrict__ w01,
                                                      const float* __restrict__ scaling,
                                                      float* __restrict__ mcl) {
  int tid = blockIdx.x * 256 + threadIdx.x;   // 32768 threads: (c, i)
  int c = tid >> 4;
  int i = tid & 15;
  float acc = 0.f;
#pragma unroll
  for (int k2 = 0; k2 < 16; ++k2) {
    int r1 = (c + NN - 2 - (k2 << 7)) & (NN - 1);
    acc = fmaf(v2[r1 * 16 + k2], w01[r1 * 16 + i], acc);
  }
  int s = c & 127;
  int j = c >> 7;
  mcl[(s * 16 + j) * 16 + i] = acc * scaling[0];
}

// ---------------------------------------------------------------------------
// Apply-stage helpers (all indices compile-time-unrollable; no macros).
// ---------------------------------------------------------------------------
__device__ __forceinline__ void sfd_loadq(float4 (&pf)[4], const float* __restrict__ x,
                                          int rb, int w0, int t) {
#pragma unroll
  for (int q = 0; q < 4; ++q) {
    int idx = t + (q << 8);                 // 0..1023 = rr*128 + ig*32 + uu
    int uu = idx & 31;
    int ig = (idx >> 5) & 3;                // i-group (4 i's)
    int rr = idx >> 7;                      // 0..7
    const float* xrow = x + (size_t)(rb + rr) * NN;
    int cb = w0 + uu + (ig << 9);           // w0+uu+128*(4*ig)
    pf[q].x = xrow[cb & (NN - 1)];
    pf[q].y = xrow[(cb + 128) & (NN - 1)];
    pf[q].z = xrow[(cb + 256) & (NN - 1)];
    pf[q].w = xrow[(cb + 384) & (NN - 1)];
  }
}

__device__ __forceinline__ void sfd_writeq(const float4 (&pf)[4], float* xs, int t) {
#pragma unroll
  for (int q = 0; q < 4; ++q) {
    int idx = t + (q << 8);
    int uu = idx & 31;
    int ig = (idx >> 5) & 3;
    int rr = idx >> 7;
    *(float4*)(xs + (rr * 32 + uu) * 20 + (ig << 2)) = pf[q];
  }
}

__device__ __forceinline__ void sfd_compute(const float* xs, int u,
                                            const float (&mc0)[16], const float (&mc1)[16],
                                            float bi0, float bi1,
                                            int rb, int c0, int c1,
                                            float* __restrict__ out) {
#pragma unroll 1
  for (int r = 0; r < 8; ++r) {
    const float4* xr = (const float4*)(xs + (r * 32 + u) * 20);
    float xv[16];
    *(float4*)(xv + 0)  = xr[0];
    *(float4*)(xv + 4)  = xr[1];
    *(float4*)(xv + 8)  = xr[2];
    *(float4*)(xv + 12) = xr[3];
    float acc0 = bi0, acc1 = bi1;
#pragma unroll
    for (int i = 0; i < 16; ++i) {
      acc0 = fmaf(xv[i], mc0[i], acc0);
      acc1 = fmaf(xv[i], mc1[i], acc1);
    }
    size_t ob = (size_t)(rb + r) * NN;
    __builtin_nontemporal_store(fmaxf(acc0, 0.f), &out[ob + c0]);
    __builtin_nontemporal_store(fmaxf(acc1, 0.f), &out[ob + c1]);
  }
}

// ---------------------------------------------------------------------------
// Apply: out[b][c] = relu( sum_i mcl[c][i] * x[b][(c-3)%128 + 128*i] + bias[c] )
// Block: strip of 32 residues (512 cols) x 32 batch rows; grid (4, 512) =
// 2048 blocks = 8 blocks/CU.  Thread (u=t&31, jp=t>>5) -> 2 cols
// c = S0+u+128*(2jp+{0,1}); 2x16 coefficients in registers (rotated by
// `shift` to absorb the mod-128 wrap so LDS slots are i-aligned).
// LDS layout xs[r][u][i] stride 20 floats: 16-B aligned -> ds_read_b128,
// odd*4 stride keeps b128 phase/bank density identical to contiguous.
//
// T14 async-STAGE split: register-prefetch chunk ch+1's 16 x-values during
// chunk ch's compute.  The vmcnt wait for the prefetch lands at the NEXT
// iteration's ds_write (after ~1K cycles of compute), hiding the ~900-cycle
// HBM latency that was previously exposed at every chunk barrier.  pfA/pfB
// alternate statically (no runtime indexing -> no scratch).
// ---------------------------------------------------------------------------
__global__ __launch_bounds__(256, 8) void sfd_apply(const float* __restrict__ x,
                                                    const float* __restrict__ mcl,
                                                    const float* __restrict__ bias,
                                                    float* __restrict__ out) {
  const int S0 = blockIdx.x << 5;             // strip base residue: 0,32,64,96
  const int b0 = blockIdx.y << 5;             // 32 batch rows per block
  const int t = threadIdx.x;
  const int u = t & 31;
  const int jp = t >> 5;                      // 0..7
  const int s = S0 + u;                       // residue (= col mod 128), < 128
  const int j0 = jp << 1;
  const int w0 = (S0 + 125) & 127;            // (S0 - 3) mod 128
  const int shift = (w0 + u) >> 7;            // 1 iff this thread's window wraps

  // 2x16 coefficients into registers, rotated by `shift`:
  // LDS slot i holds x[(s-3)%128 + 128*((i+shift)&15)].
  float mc0[16], mc1[16];
  {
    const float* r0p = mcl + ((s * 16 + j0) << 4);
#pragma unroll
    for (int i = 0; i < 16; ++i) {
      int ic = (i + shift) & 15;
      mc0[i] = r0p[ic];
      mc1[i] = r0p[16 + ic];
    }
  }
  const int c0 = s + (j0 << 7);
  const int c1 = c0 + 128;
  const float bi0 = bias[c0];
  const float bi1 = bias[c1];

  __shared__ float xs[8 * 32 * 20];           // 20480 B: 8 rows x 32 u x stride 20

  float4 pfA[4], pfB[4];

  // Software pipeline over the 4 chunks (fully static, pfA/pfB alternate):
  sfd_loadq(pfA, x, b0 + 0,  w0, t);
  sfd_writeq(pfA, xs, t);            // waits pfA loads (vmcnt), no prior readers
  sfd_loadq(pfB, x, b0 + 8,  w0, t); // in flight during compute(0)
  __syncthreads();
  sfd_compute(xs, u, mc0, mc1, bi0, bi1, b0 + 0,  c0, c1, out);
  __syncthreads();
  sfd_writeq(pfB, xs, t);            // vmcnt wait here = after compute(0)
  sfd_loadq(pfA, x, b0 + 16, w0, t); // in flight during compute(1)
  __syncthreads();
  sfd_compute(xs, u, mc0, mc1, bi0, bi1, b0 + 8,  c0, c1, out);
  __syncthreads();
  sfd_writeq(pfA, xs, t);
  sfd_loadq(pfB, x, b0 + 24, w0, t); // in flight during compute(2)
  __syncthreads();
  sfd_compute(xs, u, mc0, mc1, bi0, bi1, b0 + 16, c0, c1, out);
  __syncthreads();
  sfd_writeq(pfB, xs, t);
  __syncthreads();
  sfd_compute(xs, u, mc0, mc1, bi0, bi1, b0 + 24, c0, c1, out);
}

extern "C" void kernel_launch(void* const* d_in, const int* in_sizes, int n_in,
                              void* d_out, int out_size, void* d_ws, size_t ws_size,
                              hipStream_t stream) {
  // 0:x 1:vals0 2:vals1 3:vals2 4:rows0 5:cols0 6:rows1 7:cols1 8:rows2 9:cols2
  // 10:scaling 11:bias
  const float* x       = (const float*)d_in[0];
  const float* v0      = (const float*)d_in[1];
  const float* v1      = (const float*)d_in[2];
  const float* v2      = (const float*)d_in[3];
  const float* scaling = (const float*)d_in[10];
  const float* bias    = (const float*)d_in[11];
  float* out = (float*)d_out;

  float* w01 = (float*)d_ws;          // 2048*16 floats = 128 KiB
  float* mcl = w01 + NN * KK;         // 2048*16 floats = 128 KiB

  const int B = in_sizes[0] / NN;     // 16384

  hipLaunchKernelGGL(sfd_compose01, dim3(128), dim3(256), 0, stream, v0, v1, w01);
  hipLaunchKernelGGL(sfd_compose012, dim3(128), dim3(256), 0, stream, v2, w01, scaling, mcl);
  hipLaunchKernelGGL(sfd_apply, dim3(4, B >> 5), dim3(256), 0, stream, x, mcl, bias, out);
}

// Round 3
// 265.654 us; speedup vs baseline: 1.1195x; 1.1195x over previous
//
#include <hip/hip_runtime.h>

#define NN 2048   // factor dim
#define KK 16     // nonzeros per row

// ---------------------------------------------------------------------------
// Stage A: compose W0 @ W1 into per-column coefficient table.
// W01[c1][i] = coefficient of x[s1' + 128*i] in y1[c1], s1' = (c1-1) mod 128.
// ---------------------------------------------------------------------------
__global__ __launch_bounds__(256) void sfd_compose01(const float* __restrict__ v0,
                                                     const float* __restrict__ v1,
                                                     float* __restrict__ w01) {
  int tid = blockIdx.x * 256 + threadIdx.x;   // 32768 threads: (c1, i)
  int c1 = tid >> 4;
  int i  = tid & 15;
  int cm = (c1 + NN - 1) & (NN - 1);          // (c1 - 1) mod N
  int s1 = cm & 127;
  int t1 = cm >> 7;
  int rx = s1 + (i << 7);
  float acc = 0.f;
#pragma unroll
  for (int k1 = 0; k1 < 16; ++k1) {
    int r0 = (cm - (k1 << 7)) & (NN - 1);
    int k0 = (t1 - k1 - i) & 15;
    acc = fmaf(v1[r0 * 16 + k1], v0[rx * 16 + k0], acc);
  }
  w01[c1 * 16 + i] = acc;
}

// ---------------------------------------------------------------------------
// Stage B: compose (W0@W1) @ W2, fold in scaling, store residue-major:
// mcl[((s*16 + j)*16) + i]  for col c = s + 128*j, coefficient of
// x[((c-3) mod 128) + 128*i].
// ---------------------------------------------------------------------------
__global__ __launch_bounds__(256) void sfd_compose012(const float* __restrict__ v2,
                                                      const float* __restrict__ w01,
                                                      const float* __restrict__ scaling,
                                                      float* __restrict__ mcl) {
  int tid = blockIdx.x * 256 + threadIdx.x;   // 32768 threads: (c, i)
  int c = tid >> 4;
  int i = tid & 15;
  float acc = 0.f;
#pragma unroll
  for (int k2 = 0; k2 < 16; ++k2) {
    int r1 = (c + NN - 2 - (k2 << 7)) & (NN - 1);
    acc = fmaf(v2[r1 * 16 + k2], w01[r1 * 16 + i], acc);
  }
  int s = c & 127;
  int j = c >> 7;
  mcl[(s * 16 + j) * 16 + i] = acc * scaling[0];
}

// ---------------------------------------------------------------------------
// Apply-stage helpers (all indices compile-time-unrollable).
// ---------------------------------------------------------------------------
__device__ __forceinline__ void sfd_loadq(float4 (&pf)[4], const float* __restrict__ x,
                                          int rb, int w0, int t) {
#pragma unroll
  for (int q = 0; q < 4; ++q) {
    int idx = t + (q << 8);                 // 0..1023 = rr*128 + ig*32 + uu
    int uu = idx & 31;
    int ig = (idx >> 5) & 3;                // i-group (4 i's)
    int rr = idx >> 7;                      // 0..7
    const float* xrow = x + (size_t)(rb + rr) * NN;
    int cb = w0 + uu + (ig << 9);           // w0+uu+128*(4*ig)
    pf[q].x = xrow[cb & (NN - 1)];
    pf[q].y = xrow[(cb + 128) & (NN - 1)];
    pf[q].z = xrow[(cb + 256) & (NN - 1)];
    pf[q].w = xrow[(cb + 384) & (NN - 1)];
  }
}

__device__ __forceinline__ void sfd_writeq(const float4 (&pf)[4], float* xs, int t) {
#pragma unroll
  for (int q = 0; q < 4; ++q) {
    int idx = t + (q << 8);
    int uu = idx & 31;
    int ig = (idx >> 5) & 3;
    int rr = idx >> 7;
    *(float4*)(xs + (rr * 32 + uu) * 20 + (ig << 2)) = pf[q];
  }
}

__device__ __forceinline__ void sfd_compute(const float* xs, int u,
                                            const float (&mc0)[16], const float (&mc1)[16],
                                            float bi0, float bi1,
                                            int rb, int c0, int c1,
                                            float* __restrict__ out) {
#pragma unroll 1
  for (int r = 0; r < 8; ++r) {
    const float4* xr = (const float4*)(xs + (r * 32 + u) * 20);
    float xv[16];
    *(float4*)(xv + 0)  = xr[0];
    *(float4*)(xv + 4)  = xr[1];
    *(float4*)(xv + 8)  = xr[2];
    *(float4*)(xv + 12) = xr[3];
    float acc0 = bi0, acc1 = bi1;
#pragma unroll
    for (int i = 0; i < 16; ++i) {
      acc0 = fmaf(xv[i], mc0[i], acc0);
      acc1 = fmaf(xv[i], mc1[i], acc1);
    }
    size_t ob = (size_t)(rb + r) * NN;
    __builtin_nontemporal_store(fmaxf(acc0, 0.f), &out[ob + c0]);
    __builtin_nontemporal_store(fmaxf(acc1, 0.f), &out[ob + c1]);
  }
}

// ---------------------------------------------------------------------------
// Apply: out[b][c] = relu( sum_i mcl[c][i] * x[b][(c-3)%128 + 128*i] + bias[c] )
// Block: strip of 32 residues (512 cols) x 32 batch rows; grid (4, 512).
// Thread (u=t&31, jp=t>>5) -> 2 cols c = S0+u+128*(2jp+{0,1}); 2x16
// coefficients in registers (rotated by `shift` to absorb the mod-128 wrap).
// LDS layout xs[r][u][i] stride 20 floats: ds_read_b128, conflict-free.
//
// T14 async-STAGE pipeline: register-prefetch chunk ch+1's 16 x-values during
// chunk ch's compute, hiding the ~900-cycle HBM latency that the serial
// version exposes at every chunk barrier.
//
// launch_bounds(256, 4): Round-2 post-mortem showed (256,8) caps the
// allocator at 64 VGPR -> the pfA/pfB prefetch buffers spilled to scratch
// (+37 MB FETCH / +67 MB WRITE, +30% time).  (256,4) gives a 128-VGPR
// budget: ~100 VGPR used, no spill, ~5 blocks/CU (LDS would allow 8 but
// pipelining needs less TLP).
// ---------------------------------------------------------------------------
__global__ __launch_bounds__(256, 4) void sfd_apply(const float* __restrict__ x,
                                                    const float* __restrict__ mcl,
                                                    const float* __restrict__ bias,
                                                    float* __restrict__ out) {
  const int S0 = blockIdx.x << 5;             // strip base residue: 0,32,64,96
  const int b0 = blockIdx.y << 5;             // 32 batch rows per block
  const int t = threadIdx.x;
  const int u = t & 31;
  const int jp = t >> 5;                      // 0..7
  const int s = S0 + u;                       // residue (= col mod 128), < 128
  const int j0 = jp << 1;
  const int w0 = (S0 + 125) & 127;            // (S0 - 3) mod 128
  const int shift = (w0 + u) >> 7;            // 1 iff this thread's window wraps

  // 2x16 coefficients into registers, rotated by `shift`:
  // LDS slot i holds x[(s-3)%128 + 128*((i+shift)&15)].
  float mc0[16], mc1[16];
  {
    const float* r0p = mcl + ((s * 16 + j0) << 4);
#pragma unroll
    for (int i = 0; i < 16; ++i) {
      int ic = (i + shift) & 15;
      mc0[i] = r0p[ic];
      mc1[i] = r0p[16 + ic];
    }
  }
  const int c0 = s + (j0 << 7);
  const int c1 = c0 + 128;
  const float bi0 = bias[c0];
  const float bi1 = bias[c1];

  __shared__ float xs[8 * 32 * 20];           // 20480 B: 8 rows x 32 u x stride 20

  float4 pfA[4], pfB[4];

  // Software pipeline over the 4 chunks (fully static, pfA/pfB alternate):
  sfd_loadq(pfA, x, b0 + 0,  w0, t);
  sfd_writeq(pfA, xs, t);            // waits pfA loads (vmcnt), no prior readers
  sfd_loadq(pfB, x, b0 + 8,  w0, t); // in flight during compute(0)
  __syncthreads();
  sfd_compute(xs, u, mc0, mc1, bi0, bi1, b0 + 0,  c0, c1, out);
  __syncthreads();
  sfd_writeq(pfB, xs, t);            // vmcnt wait here = after compute(0)
  sfd_loadq(pfA, x, b0 + 16, w0, t); // in flight during compute(1)
  __syncthreads();
  sfd_compute(xs, u, mc0, mc1, bi0, bi1, b0 + 8,  c0, c1, out);
  __syncthreads();
  sfd_writeq(pfA, xs, t);
  sfd_loadq(pfB, x, b0 + 24, w0, t); // in flight during compute(2)
  __syncthreads();
  sfd_compute(xs, u, mc0, mc1, bi0, bi1, b0 + 16, c0, c1, out);
  __syncthreads();
  sfd_writeq(pfB, xs, t);
  __syncthreads();
  sfd_compute(xs, u, mc0, mc1, bi0, bi1, b0 + 24, c0, c1, out);
}

extern "C" void kernel_launch(void* const* d_in, const int* in_sizes, int n_in,
                              void* d_out, int out_size, void* d_ws, size_t ws_size,
                              hipStream_t stream) {
  // 0:x 1:vals0 2:vals1 3:vals2 4:rows0 5:cols0 6:rows1 7:cols1 8:rows2 9:cols2
  // 10:scaling 11:bias
  const float* x       = (const float*)d_in[0];
  const float* v0      = (const float*)d_in[1];
  const float* v1      = (const float*)d_in[2];
  const float* v2      = (const float*)d_in[3];
  const float* scaling = (const float*)d_in[10];
  const float* bias    = (const float*)d_in[11];
  float* out = (float*)d_out;

  float* w01 = (float*)d_ws;          // 2048*16 floats = 128 KiB
  float* mcl = w01 + NN * KK;         // 2048*16 floats = 128 KiB

  const int B = in_sizes[0] / NN;     // 16384

  hipLaunchKernelGGL(sfd_compose01, dim3(128), dim3(256), 0, stream, v0, v1, w01);
  hipLaunchKernelGGL(sfd_compose012, dim3(128), dim3(256), 0, stream, v2, w01, scaling, mcl);
  hipLaunchKernelGGL(sfd_apply, dim3(4, B >> 5), dim3(256), 0, stream, x, mcl, bias, out);
}